// Round 10
// baseline (226.420 us; speedup 1.0000x reference)
//
#include <hip/hip_runtime.h>
#include <cmath>

constexpr int N_NODES = 50000;
constexpr int N_EDGES = 800000;
constexpr int D = 128;
constexpr int CAP = 32;           // bucket capacity (Poisson(16); ovf fallback)
constexpr int OVF_CAP = 8192;

constexpr int NPART = 8;                                       // row partitions (== XCDs)
constexpr int ROWS_PER_PART = (N_NODES + NPART - 1) / NPART;   // 6250
constexpr int SEGCAP = 110000;    // per-partition segment cap (mean 100K, sigma ~300)

constexpr int PART_BLOCKS = (N_EDGES + 1023) / 1024;           // 782 (1024 edges/block)
constexpr int CAST_BLOCKS = (N_NODES * D / 8 + 255) / 256;     // 3125 (uint4/thread)
constexpr int BPB = 96;                                        // phase-B blocks per partition

// ---- workspace layout (bytes) ----
// cnt     : int[N_NODES]        @ 0            (200,000)
// ovf_cnt : int                 @ 200,000
// pcur    : int[8]              @ 200,016
// bucket  : uint[N_NODES*CAP]   @ 200,064      (6,400,000)
// ovf     : int4[OVF_CAP]       @ 6,600,064    (131,072)
// packed  : uint[N_NODES*D/2]   @ 6,731,136    (12,800,000)
// wt      : ushort[D*D]         @ 19,531,136   (32,768)
// seg     : uint2[8*SEGCAP]     @ 19,563,904   (7,040,000) -> end 26,603,904
constexpr size_t OFF_OVFCNT = 200000;
constexpr size_t OFF_PCUR   = 200016;
constexpr size_t OFF_BUCKET = 200064;
constexpr size_t OFF_OVF    = 6600064;
constexpr size_t OFF_PACKED = 6731136;
constexpr size_t OFF_WT     = 19531136;
constexpr size_t OFF_SEG    = 19563904;
constexpr size_t MEMSET_BYTES = 200048;   // cnt + ovf_cnt + pcur

typedef __attribute__((ext_vector_type(8))) short bf16x8;
typedef __attribute__((ext_vector_type(4))) float f32x4;

__device__ __forceinline__ unsigned bf16rn(float f) {
    unsigned u = __float_as_uint(f);
    return (u + 0x7fffu + ((u >> 16) & 1u)) >> 16;   // round-to-nearest-even
}
__device__ __forceinline__ float bf_lo(unsigned u) { return __uint_as_float(u << 16); }
__device__ __forceinline__ float bf_hi(unsigned u) { return __uint_as_float(u & 0xffff0000u); }

// val in [0, 1/16) -> 16-bit fixed point (x 2^20). quant step 2^-20.
__device__ __forceinline__ unsigned enc_val(float v) {
    int m = (int)(v * 1048576.0f + 0.5f);
    if (m > 65535) m = 65535;
    if (m < 0) m = 0;
    return (unsigned)m;
}

// ---------------------------------------------------------------------------
// K1 (fused phase A): blocks [0, PART_BLOCKS): classify 1024 edges/block by
// partition p = r/6250 and append (r, ent) compacted into 8 dense segments.
// Per-wave ballots give ranks; per-block LDS aggregation means only 8 global
// atomics per block. Wave-contiguous writes keep segment lines single-block
// owned (no cross-XCD dirty sharing).
// Blocks [PART, PART+CAST): cast input fp32 -> packed bf16 pairs.
// Last block: W fp32 -> bf16 W^T.
// ---------------------------------------------------------------------------
__global__ __launch_bounds__(256) void partition_cast(
    const int* __restrict__ row, const int* __restrict__ col,
    const float* __restrict__ vals, const float* __restrict__ input,
    const float* __restrict__ weight,
    int* __restrict__ pcur, uint2* __restrict__ seg,
    int* __restrict__ ovf_cnt, int4* __restrict__ ovf,
    unsigned* __restrict__ packed, ushort* __restrict__ wt)
{
    if (blockIdx.x < PART_BLOCKS) {
        __shared__ int wcnt[4][8];
        __shared__ int wbase[4][8];
        const int tid = threadIdx.x;
        const int wave = tid >> 6;
        const int lane = tid & 63;

        int r[4]; unsigned ent[4]; int pe[4];
        #pragma unroll
        for (int it = 0; it < 4; ++it) {
            int e = blockIdx.x * 1024 + it * 256 + tid;
            bool ok = e < N_EDGES;
            r[it] = ok ? row[e] : -1;
            int c   = ok ? col[e] : 0;
            float v = ok ? vals[e] : 0.f;
            ent[it] = (unsigned)c | (enc_val(v) << 16);
            pe[it]  = ok ? (r[it] / ROWS_PER_PART) : -1;
        }

        // pass 1: per-wave per-partition counts
        int cw[8] = {};
        #pragma unroll
        for (int it = 0; it < 4; ++it) {
            #pragma unroll
            for (int p = 0; p < 8; ++p)
                cw[p] += __popcll(__ballot(pe[it] == p));
        }
        if (lane < 8) wcnt[wave][lane] = cw[lane];
        __syncthreads();

        // block leaders: one global atomic per partition, then wave bases
        if (tid < 8) {
            int t0 = wcnt[0][tid], t1 = wcnt[1][tid];
            int t2 = wcnt[2][tid], t3 = wcnt[3][tid];
            int base = atomicAdd(&pcur[tid], t0 + t1 + t2 + t3);
            wbase[0][tid] = base;
            wbase[1][tid] = base + t0;
            wbase[2][tid] = base + t0 + t1;
            wbase[3][tid] = base + t0 + t1 + t2;
        }
        __syncthreads();

        // pass 2: ranked compacted writes
        int off[8];
        #pragma unroll
        for (int p = 0; p < 8; ++p) off[p] = wbase[wave][p];
        const unsigned long long lmask = (1ULL << lane) - 1ULL;
        #pragma unroll
        for (int it = 0; it < 4; ++it) {
            unsigned long long m[8];
            #pragma unroll
            for (int p = 0; p < 8; ++p) m[p] = __ballot(pe[it] == p);
            if (pe[it] >= 0) {
                int rank = __popcll(m[pe[it]] & lmask);
                int idx = off[pe[it]] + rank;
                if (idx < SEGCAP) {
                    seg[(size_t)pe[it] * SEGCAP + idx] =
                        make_uint2((unsigned)r[it], ent[it]);
                } else {
                    int o = atomicAdd(ovf_cnt, 1);
                    if (o < OVF_CAP) ovf[o] = make_int4(r[it], (int)(ent[it] & 0xffffu),
                        __float_as_int((float)(ent[it] >> 16) * (1.0f / 1048576.0f)), 0);
                }
            }
            #pragma unroll
            for (int p = 0; p < 8; ++p) off[p] += __popcll(m[p]);
        }
    } else if (blockIdx.x < PART_BLOCKS + CAST_BLOCKS) {
        int i = (blockIdx.x - PART_BLOCKS) * 256 + threadIdx.x;
        if (i >= N_NODES * D / 8) return;
        const float4* f = (const float4*)(input + (size_t)i * 8);
        float4 a = f[0], b = f[1];
        uint4 o;
        o.x = bf16rn(a.x) | (bf16rn(a.y) << 16);
        o.y = bf16rn(a.z) | (bf16rn(a.w) << 16);
        o.z = bf16rn(b.x) | (bf16rn(b.y) << 16);
        o.w = bf16rn(b.z) | (bf16rn(b.w) << 16);
        ((uint4*)packed)[i] = o;
    } else {
        // W (row-major [k][n]) -> wt bf16 [n][k]; 16384 elems, 64/thread.
        #pragma unroll
        for (int j = 0; j < 64; ++j) {
            int idx = threadIdx.x + j * 256;
            int k = idx >> 7, n = idx & 127;
            wt[n * 128 + k] = (ushort)bf16rn(weight[idx]);
        }
    }
}

// ---------------------------------------------------------------------------
// K2 (phase B): bucket build from dense per-partition segments. Partition
// p = blockIdx&7 (round-robin -> one XCD owns a partition's cnt/bucket
// lines; perf heuristic only). Coalesced segment reads, every lane active,
// 4-deep atomic+store ILP.
// ---------------------------------------------------------------------------
__global__ __launch_bounds__(256) void seg_scatter(
    const int* __restrict__ pcur, const uint2* __restrict__ seg,
    int* __restrict__ cnt, unsigned* __restrict__ bucket,
    int* __restrict__ ovf_cnt, int4* __restrict__ ovf)
{
    const int p  = blockIdx.x & (NPART - 1);
    const int nb = blockIdx.x >> 3;
    int n = pcur[p]; if (n > SEGCAP) n = SEGCAP;
    const uint2* s = seg + (size_t)p * SEGCAP;

    for (int i0 = (nb * 256 + threadIdx.x) * 4; i0 < n; i0 += BPB * 256 * 4) {
        int rem = n - i0;
        uint2 e[4];
        #pragma unroll
        for (int k = 0; k < 4; ++k)
            e[k] = (k < rem) ? s[i0 + k] : make_uint2(0u, 0u);
        int pos[4];
        #pragma unroll
        for (int k = 0; k < 4; ++k)
            pos[k] = (k < rem) ? atomicAdd(&cnt[e[k].x], 1) : 0;
        #pragma unroll
        for (int k = 0; k < 4; ++k) {
            if (k >= rem) continue;
            if (pos[k] < CAP) {
                bucket[(size_t)e[k].x * CAP + pos[k]] = e[k].y;
            } else {
                int o = atomicAdd(ovf_cnt, 1);
                if (o < OVF_CAP) ovf[o] = make_int4((int)e[k].x, (int)(e[k].y & 0xffffu),
                    __float_as_int((float)(e[k].y >> 16) * (1.0f / 1048576.0f)), 0);
            }
        }
    }
}

// ---------------------------------------------------------------------------
// K3: pull-gather (bf16 operand) + support blend. One wave per row.
// Slot h (lane>>4) owns a contiguous quarter of the bucket entries; per
// iteration 4 same-line bucket reads then 4 independent row fetches in
// flight (padding entries have v=0). Slots combined with shfl_xor(16|32).
// Writes support (fp32) into d_out; K5 consumes in place.
// ---------------------------------------------------------------------------
__global__ __launch_bounds__(256) void gather_support(
    const unsigned* __restrict__ packed,
    const float* __restrict__ h0,
    const float* __restrict__ alpha_p,
    const int* __restrict__ cnt,
    const unsigned* __restrict__ bucket,
    float* __restrict__ support)
{
    const float alpha = *alpha_p;
    const float oma = 1.0f - alpha;
    const int wv   = threadIdx.x >> 6;
    const int lane = threadIdx.x & 63;
    const int q    = lane & 15;
    const int slot = lane >> 4;

    const int g = blockIdx.x * 4 + wv;
    if (g >= N_NODES) return;

    int n = cnt[g];
    if (n > CAP) n = CAP;
    const unsigned* b = bucket + (size_t)g * CAP;
    const uint4* pk = (const uint4*)packed;           // 16 uint4 per row

    const int q4 = (n + 3) >> 2;                      // entries per slot
    const int s0 = slot * q4;
    int s1 = s0 + q4; if (s1 > n) s1 = n;

    float acc[8] = {0.f, 0.f, 0.f, 0.f, 0.f, 0.f, 0.f, 0.f};
    for (int e = s0; e < s1; e += 4) {
        int rem = s1 - e;
        unsigned m0 = b[e];
        unsigned m1 = (rem > 1) ? b[e + 1] : 0u;
        unsigned m2 = (rem > 2) ? b[e + 2] : 0u;
        unsigned m3 = (rem > 3) ? b[e + 3] : 0u;
        uint4 x0 = pk[(size_t)(m0 & 0xffffu) * 16 + q];
        uint4 x1 = pk[(size_t)(m1 & 0xffffu) * 16 + q];
        uint4 x2 = pk[(size_t)(m2 & 0xffffu) * 16 + q];
        uint4 x3 = pk[(size_t)(m3 & 0xffffu) * 16 + q];
        float v0 = (float)(m0 >> 16) * (1.0f / 1048576.0f);
        float v1 = (float)(m1 >> 16) * (1.0f / 1048576.0f);
        float v2 = (float)(m2 >> 16) * (1.0f / 1048576.0f);
        float v3 = (float)(m3 >> 16) * (1.0f / 1048576.0f);
        acc[0] += v0 * bf_lo(x0.x); acc[1] += v0 * bf_hi(x0.x);
        acc[2] += v0 * bf_lo(x0.y); acc[3] += v0 * bf_hi(x0.y);
        acc[4] += v0 * bf_lo(x0.z); acc[5] += v0 * bf_hi(x0.z);
        acc[6] += v0 * bf_lo(x0.w); acc[7] += v0 * bf_hi(x0.w);
        acc[0] += v1 * bf_lo(x1.x); acc[1] += v1 * bf_hi(x1.x);
        acc[2] += v1 * bf_lo(x1.y); acc[3] += v1 * bf_hi(x1.y);
        acc[4] += v1 * bf_lo(x1.z); acc[5] += v1 * bf_hi(x1.z);
        acc[6] += v1 * bf_lo(x1.w); acc[7] += v1 * bf_hi(x1.w);
        acc[0] += v2 * bf_lo(x2.x); acc[1] += v2 * bf_hi(x2.x);
        acc[2] += v2 * bf_lo(x2.y); acc[3] += v2 * bf_hi(x2.y);
        acc[4] += v2 * bf_lo(x2.z); acc[5] += v2 * bf_hi(x2.z);
        acc[6] += v2 * bf_lo(x2.w); acc[7] += v2 * bf_hi(x2.w);
        acc[0] += v3 * bf_lo(x3.x); acc[1] += v3 * bf_hi(x3.x);
        acc[2] += v3 * bf_lo(x3.y); acc[3] += v3 * bf_hi(x3.y);
        acc[4] += v3 * bf_lo(x3.z); acc[5] += v3 * bf_hi(x3.z);
        acc[6] += v3 * bf_lo(x3.w); acc[7] += v3 * bf_hi(x3.w);
    }
    #pragma unroll
    for (int j = 0; j < 8; ++j) {
        acc[j] += __shfl_xor(acc[j], 16);
        acc[j] += __shfl_xor(acc[j], 32);
    }
    if (slot == 0) {                                  // lanes 0..15
        const float* hp = h0 + (size_t)g * D + q * 8;
        float4 ha = *(const float4*)(hp);
        float4 hb = *(const float4*)(hp + 4);
        float* sp = support + (size_t)g * D + q * 8;
        float4 sa, sb;
        sa.x = oma * acc[0] + alpha * ha.x;
        sa.y = oma * acc[1] + alpha * ha.y;
        sa.z = oma * acc[2] + alpha * ha.z;
        sa.w = oma * acc[3] + alpha * ha.w;
        sb.x = oma * acc[4] + alpha * hb.x;
        sb.y = oma * acc[5] + alpha * hb.y;
        sb.z = oma * acc[6] + alpha * hb.z;
        sb.w = oma * acc[7] + alpha * hb.w;
        *(float4*)(sp) = sa;
        *(float4*)(sp + 4) = sb;
    }
}

// ---------------------------------------------------------------------------
// K4: apply overflow edges (expected ~0; safety net).
// ---------------------------------------------------------------------------
__global__ __launch_bounds__(256) void ovf_apply(
    const float* __restrict__ input,
    const float* __restrict__ alpha_p,
    const int* __restrict__ ovf_cnt,
    const int4* __restrict__ ovf,
    float* __restrict__ support)
{
    int n = *ovf_cnt;
    if (n > OVF_CAP) n = OVF_CAP;
    const float oma = 1.0f - *alpha_p;
    for (int i = blockIdx.x * 256 + threadIdx.x; i < n * 2; i += gridDim.x * 256) {
        int idx = i >> 1, part = i & 1;
        int4 m = ovf[idx];
        float v = oma * __int_as_float(m.z);
        const float* x = input + (size_t)m.y * D + part * 64;
        float* s = support + (size_t)m.x * D + part * 64;
        for (int k = 0; k < 64; ++k) atomicAdd(&s[k], v * x[k]);
    }
}

// ---------------------------------------------------------------------------
// K5: MFMA bf16 in-place GEMM + epilogue on d_out (unchanged from round 8).
//   data[r] (out) = theta * bf16(data[r]) @ bf16(W) + (1-theta) * data[r]
// LDS: sA 64x136 bf16 + sB (W^T) 128x136 bf16 = 52 KB -> 3 blocks/CU.
// ---------------------------------------------------------------------------
__global__ __launch_bounds__(256) void gemm_mfma(
    const ushort* __restrict__ wt,
    const float* __restrict__ lamda_p,
    const int* __restrict__ l_p,
    float* __restrict__ data)
{
    constexpr int SP = 136;                // padded LDS row stride (bf16 units)
    __shared__ ushort sA[64 * SP];         // 17,408 B
    __shared__ ushort sB[128 * SP];        // 34,816 B

    const int tid = threadIdx.x;
    const float lamda = *lamda_p;
    const float theta = logf(lamda / (float)(*l_p) + 1.0f);
    const float omt = 1.0f - theta;
    const int row0 = blockIdx.x * 64;

    #pragma unroll
    for (int j = 0; j < 8; ++j) {
        int idx = j * 256 + tid;
        int n  = idx >> 4;
        int k8 = (idx & 15) << 3;
        *(uint4*)(&sB[n * SP + k8]) = ((const uint4*)wt)[idx];
    }
    #pragma unroll
    for (int j = 0; j < 8; ++j) {
        int idx = j * 256 + tid;
        int rr = idx >> 5;
        int c4 = (idx & 31) << 2;
        int g = row0 + rr;
        float4 s = make_float4(0.f, 0.f, 0.f, 0.f);
        if (g < N_NODES) s = *(const float4*)(data + (size_t)g * D + c4);
        uint2 pkv;
        pkv.x = bf16rn(s.x) | (bf16rn(s.y) << 16);
        pkv.y = bf16rn(s.z) | (bf16rn(s.w) << 16);
        *(uint2*)(&sA[rr * SP + c4]) = pkv;
    }
    __syncthreads();

    const int wave = tid >> 6;
    const int lane = tid & 63;
    const int m    = lane & 15;
    const int quad = lane >> 4;
    const int arow = wave * 16 + m;

    f32x4 acc[8] = {};                      // 8 N-tiles of 16 cols
    #pragma unroll
    for (int kb = 0; kb < 4; ++kb) {
        bf16x8 a = *(const bf16x8*)(&sA[arow * SP + kb * 32 + quad * 8]);
        #pragma unroll
        for (int nt = 0; nt < 8; ++nt) {
            bf16x8 b = *(const bf16x8*)(&sB[(nt * 16 + m) * SP + kb * 32 + quad * 8]);
            acc[nt] = __builtin_amdgcn_mfma_f32_16x16x32_bf16(a, b, acc[nt], 0, 0, 0);
        }
    }

    const int gbase = row0 + wave * 16 + quad * 4;
    #pragma unroll
    for (int nt = 0; nt < 8; ++nt) {
        int colb = nt * 16 + m;
        #pragma unroll
        for (int i = 0; i < 4; ++i) {
            int g = gbase + i;
            if (g < N_NODES) {
                size_t off = (size_t)g * D + colb;
                float s = data[off];
                data[off] = theta * acc[nt][i] + omt * s;
            }
        }
    }
}

extern "C" void kernel_launch(void* const* d_in, const int* in_sizes, int n_in,
                              void* d_out, int out_size, void* d_ws, size_t ws_size,
                              hipStream_t stream) {
    const float* input  = (const float*)d_in[0];
    const float* h0     = (const float*)d_in[1];
    const float* vals   = (const float*)d_in[2];
    const float* weight = (const float*)d_in[3];
    const float* lamda  = (const float*)d_in[4];
    const float* alpha  = (const float*)d_in[5];
    const int*   row    = (const int*)d_in[6];
    const int*   col    = (const int*)d_in[7];
    const int*   l      = (const int*)d_in[8];
    float* out = (float*)d_out;

    char* ws = (char*)d_ws;
    int*      cnt     = (int*)ws;
    int*      ovf_cnt = (int*)(ws + OFF_OVFCNT);
    int*      pcur    = (int*)(ws + OFF_PCUR);
    unsigned* bucket  = (unsigned*)(ws + OFF_BUCKET);
    int4*     ovf     = (int4*)(ws + OFF_OVF);
    unsigned* packed  = (unsigned*)(ws + OFF_PACKED);
    ushort*   wt      = (ushort*)(ws + OFF_WT);
    uint2*    seg     = (uint2*)(ws + OFF_SEG);

    // zero cnt + ovf_cnt + pcur (ws is re-poisoned to 0xAA before every launch)
    hipMemsetAsync(ws, 0, MEMSET_BYTES, stream);

    partition_cast<<<PART_BLOCKS + CAST_BLOCKS + 1, 256, 0, stream>>>(
        row, col, vals, input, weight, pcur, seg, ovf_cnt, ovf, packed, wt);

    seg_scatter<<<NPART * BPB, 256, 0, stream>>>(
        pcur, seg, cnt, bucket, ovf_cnt, ovf);

    int gatherb = (N_NODES + 3) / 4;                 // 12500 (4 waves/block)
    gather_support<<<gatherb, 256, 0, stream>>>(packed, h0, alpha, cnt, bucket, out);

    ovf_apply<<<8, 256, 0, stream>>>(input, alpha, ovf_cnt, ovf, out);

    int gemmb = (N_NODES + 63) / 64;                 // 782
    gemm_mfma<<<gemmb, 256, 0, stream>>>(wt, lamda, l, out);
}